// Round 1
// baseline (263.880 us; speedup 1.0000x reference)
//
#include <hip/hip_runtime.h>
#include <math.h>

#define NQ 14
#define DEPTH 6
#define DIM 16384            // 2^NQ
#define NGATES (NQ * DEPTH)  // 84
#define BLOCK 1024
#define ELEMS_PER_THREAD (DIM / BLOCK)      // 16
#define PAIRS_PER_THREAD (DIM / 2 / BLOCK)  // 8

// One workgroup per batch item. Full statevector in LDS (float2 = re,im).
// Gates: RY butterflies, one __syncthreads per gate. CZ sign fused into the
// last gate of each layer (bit position p=0 there, pairs are (even, even+1)).
__global__ __launch_bounds__(BLOCK, 1) void qsim_kernel(
    const float* __restrict__ x,       // (512, 14)
    const float* __restrict__ theta,   // (84,)
    const float* __restrict__ head_w,  // (2, 14)
    const float* __restrict__ head_b,  // (2,)
    float* __restrict__ out)           // (512, 2)
{
    extern __shared__ float2 st[];     // DIM * 8 bytes = 128 KiB (dynamic)
    __shared__ float2 gate[NGATES];    // (cos, sin) per gate
    __shared__ float  wtab[2][2][128]; // [out][lo/hi][7-bit idx] head-weight table
    __shared__ float  redbuf[32];      // per-wave partial logits (16 waves x 2)

    const int t = threadIdx.x;
    const int b = blockIdx.x;

    // ---- one-time per-block precompute (before first sync) ----
    if (t < NGATES) {
        float a = 0.5f * theta[t];
        gate[t] = make_float2(cosf(a), sinf(a));
    }
    if (t < 512) {
        // w_eff[o](k) = sum_{j=0..13} (1 - 2*((k>>j)&1)) * head_w[o][j]
        // split k into lo 7 bits (j=0..6) and hi 7 bits (j=7..13)
        int o    = t >> 8;        // 0..1
        int half = (t >> 7) & 1;  // 0 = lo, 1 = hi
        int idx  = t & 127;
        float s = 0.f;
        #pragma unroll
        for (int jj = 0; jj < 7; ++jj) {
            int j = half ? (jj + 7) : jj;
            float w = head_w[o * NQ + j];
            s += ((idx >> jj) & 1) ? -w : w;
        }
        wtab[o][half][idx] = s;
    }

    // ---- initial product state: RX(x_q) on |0..0> ----
    // amp(k) = [prod_q (bit_q(k) ? sin(x_q/2) : cos(x_q/2))] * (-i)^popcount(k)
    // bit_q(k) = (k >> (13 - q)) & 1   (qubit 0 = most significant bit)
    float cq[NQ], sq[NQ];
    #pragma unroll
    for (int q = 0; q < NQ; ++q) {
        float xv = 0.5f * x[b * NQ + q];
        cq[q] = cosf(xv);
        sq[q] = sinf(xv);
    }
    for (int n = 0; n < ELEMS_PER_THREAD; ++n) {
        int k = t + n * BLOCK;
        float m = 1.f;
        #pragma unroll
        for (int q = 0; q < NQ; ++q) {
            m *= ((k >> (NQ - 1 - q)) & 1) ? sq[q] : cq[q];
        }
        int pc = __popc(k) & 3;   // (-i)^pc
        float re = (pc == 0) ? m : ((pc == 2) ? -m : 0.f);
        float im = (pc == 1) ? -m : ((pc == 3) ? m : 0.f);
        st[k] = make_float2(re, im);
    }
    __syncthreads();

    // ---- gate applications ----
    for (int d = 0; d < DEPTH; ++d) {
        for (int q = 0; q < NQ; ++q) {
            const int p = NQ - 1 - q;        // bit position of qubit q
            const float2 g = gate[d * NQ + q];
            const bool last = (q == NQ - 1); // fuse CZ sign here (p == 0)
            #pragma unroll
            for (int n = 0; n < PAIRS_PER_THREAD; ++n) {
                int j  = t + n * BLOCK;                    // pair index
                int lo = j & ((1 << p) - 1);
                int i0 = ((j >> p) << (p + 1)) | lo;
                int i1 = i0 | (1 << p);
                float2 a0 = st[i0];
                float2 a1 = st[i1];
                float2 n0, n1;
                n0.x = g.x * a0.x - g.y * a1.x;
                n0.y = g.x * a0.y - g.y * a1.y;
                n1.x = g.y * a0.x + g.x * a1.x;
                n1.y = g.y * a0.y + g.x * a1.y;
                if (last) {
                    // CZ chain sign: parity of popcount(k & (k>>1))
                    float s0 = (__popc(i0 & (i0 >> 1)) & 1) ? -1.f : 1.f;
                    float s1 = (__popc(i1 & (i1 >> 1)) & 1) ? -1.f : 1.f;
                    n0.x *= s0; n0.y *= s0;
                    n1.x *= s1; n1.y *= s1;
                }
                st[i0] = n0;
                st[i1] = n1;
            }
            __syncthreads();
        }
    }

    // ---- readout: probs -> logits via split weight tables ----
    float l0 = 0.f, l1 = 0.f;
    for (int n = 0; n < ELEMS_PER_THREAD; ++n) {
        int k = t + n * BLOCK;
        float2 a = st[k];
        float pr = a.x * a.x + a.y * a.y;
        int klo = k & 127;
        int khi = k >> 7;
        l0 += pr * (wtab[0][0][klo] + wtab[0][1][khi]);
        l1 += pr * (wtab[1][0][klo] + wtab[1][1][khi]);
    }
    // wave (64-lane) reduction
    #pragma unroll
    for (int off = 32; off > 0; off >>= 1) {
        l0 += __shfl_xor(l0, off);
        l1 += __shfl_xor(l1, off);
    }
    const int wave = t >> 6;
    const int lane = t & 63;
    if (lane == 0) { redbuf[wave] = l0; redbuf[16 + wave] = l1; }
    __syncthreads();
    if (t == 0) {
        float a0 = head_b[0], a1 = head_b[1];
        #pragma unroll
        for (int w = 0; w < 16; ++w) { a0 += redbuf[w]; a1 += redbuf[16 + w]; }
        out[b * 2 + 0] = a0;
        out[b * 2 + 1] = a1;
    }
}

extern "C" void kernel_launch(void* const* d_in, const int* in_sizes, int n_in,
                              void* d_out, int out_size, void* d_ws, size_t ws_size,
                              hipStream_t stream) {
    const float* x      = (const float*)d_in[0];
    const float* theta  = (const float*)d_in[1];
    const float* head_w = (const float*)d_in[2];
    const float* head_b = (const float*)d_in[3];
    float* out = (float*)d_out;
    const int batch = in_sizes[0] / NQ;  // 512
    qsim_kernel<<<batch, BLOCK, DIM * sizeof(float2), stream>>>(
        x, theta, head_w, head_b, out);
}

// Round 2
// 85.513 us; speedup vs baseline: 3.0859x; 3.0859x over previous
//
#include <hip/hip_runtime.h>
#include <math.h>

#define NQ 14
#define DEPTH 6
#define DIM 16384
#define BLOCK 1024
#define WIN 18   // float2 per 16-amp window (16 data + 2 pad) -> bank-conflict-free

// Butterfly for RY: u' = c*u - s*v ; v' = s*u + c*v (componentwise on re/im)
__device__ __forceinline__ void bfly(float2& u, float2& v, float c, float s) {
    float ux = u.x, uy = u.y, vx = v.x, vy = v.y;
    u.x = c * ux - s * vx;  u.y = c * uy - s * vy;
    v.x = s * ux + c * vx;  v.y = s * uy + c * vy;
}

// Statevector index convention: qubit q sits at bit position p = 13 - q.
// LDS layout: amp k stored at float2 slot  WIN*(k>>4) + (k&15)  (padded windows).
__global__ __launch_bounds__(BLOCK, 4) void qsim_kernel(
    const float* __restrict__ x,       // (512, 14)
    const float* __restrict__ theta,   // (84,)
    const float* __restrict__ head_w,  // (2, 14)
    const float* __restrict__ head_b,  // (2,)
    float* __restrict__ out)           // (512, 2)
{
    extern __shared__ __align__(16) float2 st[];  // 1024 * WIN * 8 = 147456 B
    __shared__ float2 gate[DEPTH * 16];           // (c,s) indexed [d*16 + bitpos]
    __shared__ float  redbuf[32];

    const int t = threadIdx.x;
    const int b = blockIdx.x;

    if (t < DEPTH * NQ) {
        int d = t / NQ, q = t % NQ;
        float hg = 0.5f * theta[t];
        gate[d * 16 + (13 - q)] = make_float2(cosf(hg), sinf(hg));
    }
    __syncthreads();

    // per-qubit half-angle cos/sin of the input encoding
    float cq[NQ], sq[NQ];
    #pragma unroll
    for (int q = 0; q < NQ; ++q) {
        float h = 0.5f * x[b * NQ + q];
        cq[q] = cosf(h); sq[q] = sinf(h);
    }

    // ---- initial state directly in registers, pass-A ownership: k = (t<<4)|l
    // amp(k) = [prod_p bit_p ? sin : cos] * (-i)^popc(k)
    float Mt = 1.f;
    #pragma unroll
    for (int p = 4; p < 14; ++p)
        Mt *= ((t >> (p - 4)) & 1) ? sq[13 - p] : cq[13 - p];
    const int pct = __popc(t);
    float2 a[16];
    #pragma unroll
    for (int l = 0; l < 16; ++l) {
        float m = Mt;
        #pragma unroll
        for (int p = 0; p < 4; ++p)
            m *= ((l >> p) & 1) ? sq[13 - p] : cq[13 - p];
        int e = (pct + __popc(l)) & 3;     // (-i)^e
        a[l].x = (e == 0) ? m : ((e == 2) ? -m : 0.f);
        a[l].y = (e == 1) ? -m : ((e == 3) ? m : 0.f);
    }

    // CZ-chain signs in pass-D layout: k = (l&3) | (t<<2) | ((l>>2)<<12)
    float czs[16];
    #pragma unroll
    for (int l = 0; l < 16; ++l) {
        int k = (l & 3) | (t << 2) | ((l >> 2) << 12);
        czs[l] = (__popc(k & (k >> 1)) & 1) ? -1.f : 1.f;
    }

    // per-pass LDS base pointers (slot = WIN*(k>>4) + (k&15))
    float2* const pA = st + t * WIN;                                        // l = bits 0-3
    float2* const pB = st + (t >> 4) * (16 * WIN) + (t & 15);               // l = bits 4-7, stride WIN
    float2* const pC = st + (((t >> 4) & 15) + ((t >> 8) << 8)) * WIN + (t & 15); // l = bits 8-11, stride 16*WIN
    float2* const pD = st + (t >> 2) * WIN + ((t & 3) << 2);                // bits 12,13 + filler 0,1

    #pragma unroll 1
    for (int d = 0; d < DEPTH; ++d) {
        const float2* g = &gate[d * 16];

        // ---- pass A: gate bits 0..3 ----
        if (d > 0) {
            const float4* r4 = (const float4*)pA;
            #pragma unroll
            for (int j = 0; j < 8; ++j) {
                float4 v = r4[j];
                a[2*j]   = make_float2(v.x, v.y);
                a[2*j+1] = make_float2(v.z, v.w);
            }
        }
        #pragma unroll
        for (int p = 0; p < 4; ++p) {
            float2 gg = g[p];
            #pragma unroll
            for (int l = 0; l < 16; ++l)
                if (!(l & (1 << p)))
                    bfly(a[l], a[l | (1 << p)], gg.x, gg.y);
        }
        {
            float4* w4 = (float4*)pA;
            #pragma unroll
            for (int j = 0; j < 8; ++j)
                w4[j] = make_float4(a[2*j].x, a[2*j].y, a[2*j+1].x, a[2*j+1].y);
        }
        __syncthreads();

        // ---- pass B: gate bits 4..7 ----
        #pragma unroll
        for (int l = 0; l < 16; ++l) a[l] = pB[l * WIN];
        #pragma unroll
        for (int p = 0; p < 4; ++p) {
            float2 gg = g[4 + p];
            #pragma unroll
            for (int l = 0; l < 16; ++l)
                if (!(l & (1 << p)))
                    bfly(a[l], a[l | (1 << p)], gg.x, gg.y);
        }
        #pragma unroll
        for (int l = 0; l < 16; ++l) pB[l * WIN] = a[l];
        __syncthreads();

        // ---- pass C: gate bits 8..11 ----
        #pragma unroll
        for (int l = 0; l < 16; ++l) a[l] = pC[l * (16 * WIN)];
        #pragma unroll
        for (int p = 0; p < 4; ++p) {
            float2 gg = g[8 + p];
            #pragma unroll
            for (int l = 0; l < 16; ++l)
                if (!(l & (1 << p)))
                    bfly(a[l], a[l | (1 << p)], gg.x, gg.y);
        }
        #pragma unroll
        for (int l = 0; l < 16; ++l) pC[l * (16 * WIN)] = a[l];
        __syncthreads();

        // ---- pass D: gate bits 12,13 (l = (hi<<2)|lo, hi = k bits 12,13; lo = k bits 0,1) ----
        #pragma unroll
        for (int hi = 0; hi < 4; ++hi) {
            const float4* r4 = (const float4*)(pD + hi * (256 * WIN));
            float4 v0 = r4[0], v1 = r4[1];
            a[4*hi+0] = make_float2(v0.x, v0.y);
            a[4*hi+1] = make_float2(v0.z, v0.w);
            a[4*hi+2] = make_float2(v1.x, v1.y);
            a[4*hi+3] = make_float2(v1.z, v1.w);
        }
        {
            float2 g12 = g[12], g13 = g[13];
            #pragma unroll
            for (int l = 0; l < 16; ++l)
                if (!(l & 4)) bfly(a[l], a[l | 4], g12.x, g12.y);
            #pragma unroll
            for (int l = 0; l < 16; ++l)
                if (!(l & 8)) bfly(a[l], a[l | 8], g13.x, g13.y);
        }
        if (d < DEPTH - 1) {
            // CZ diagonal (skipped on last layer: probs are sign-invariant)
            #pragma unroll
            for (int l = 0; l < 16; ++l) { a[l].x *= czs[l]; a[l].y *= czs[l]; }
            #pragma unroll
            for (int hi = 0; hi < 4; ++hi) {
                float4* w4 = (float4*)(pD + hi * (256 * WIN));
                w4[0] = make_float4(a[4*hi+0].x, a[4*hi+0].y, a[4*hi+1].x, a[4*hi+1].y);
                w4[1] = make_float4(a[4*hi+2].x, a[4*hi+2].y, a[4*hi+3].x, a[4*hi+3].y);
            }
            __syncthreads();
        }
    }

    // ---- readout from registers (pass-D layout) ----
    // logits[o] = b[o] + sum_k pr(k) * sum_p hw[o][p]*(1-2*bit_p(k))
    float h0[NQ], h1[NQ];
    #pragma unroll
    for (int p = 0; p < NQ; ++p) { h0[p] = head_w[p]; h1[p] = head_w[NQ + p]; }
    float base0 = 0.f, base1 = 0.f;
    #pragma unroll
    for (int p = 2; p < 12; ++p) {   // bits 2..11 come from t
        float sg = ((t >> (p - 2)) & 1) ? -1.f : 1.f;
        base0 += sg * h0[p]; base1 += sg * h1[p];
    }
    float l0 = 0.f, l1 = 0.f;
    #pragma unroll
    for (int l = 0; l < 16; ++l) {
        float pr = a[l].x * a[l].x + a[l].y * a[l].y;
        float w0 = base0 + ((l & 1) ? -h0[0] : h0[0]) + ((l & 2) ? -h0[1] : h0[1])
                         + ((l & 4) ? -h0[12] : h0[12]) + ((l & 8) ? -h0[13] : h0[13]);
        float w1 = base1 + ((l & 1) ? -h1[0] : h1[0]) + ((l & 2) ? -h1[1] : h1[1])
                         + ((l & 4) ? -h1[12] : h1[12]) + ((l & 8) ? -h1[13] : h1[13]);
        l0 += pr * w0; l1 += pr * w1;
    }
    #pragma unroll
    for (int off = 32; off > 0; off >>= 1) {
        l0 += __shfl_xor(l0, off);
        l1 += __shfl_xor(l1, off);
    }
    if ((t & 63) == 0) { redbuf[t >> 6] = l0; redbuf[16 + (t >> 6)] = l1; }
    __syncthreads();
    if (t == 0) {
        float s0 = head_b[0], s1 = head_b[1];
        #pragma unroll
        for (int w = 0; w < 16; ++w) { s0 += redbuf[w]; s1 += redbuf[16 + w]; }
        out[b * 2 + 0] = s0;
        out[b * 2 + 1] = s1;
    }
}

extern "C" void kernel_launch(void* const* d_in, const int* in_sizes, int n_in,
                              void* d_out, int out_size, void* d_ws, size_t ws_size,
                              hipStream_t stream) {
    const float* x      = (const float*)d_in[0];
    const float* theta  = (const float*)d_in[1];
    const float* head_w = (const float*)d_in[2];
    const float* head_b = (const float*)d_in[3];
    float* out = (float*)d_out;
    const int batch = in_sizes[0] / NQ;  // 512
    const size_t lds_bytes = (size_t)(DIM / 16) * WIN * sizeof(float2);  // 147456
    qsim_kernel<<<batch, BLOCK, lds_bytes, stream>>>(x, theta, head_w, head_b, out);
}